// Round 5
// baseline (581.774 us; speedup 1.0000x reference)
//
#include <hip/hip_runtime.h>
#include <hip/hip_bf16.h>

#define IN_DIM  128
#define HID_DIM 128
#define OUT_DIM 64

typedef unsigned short ushort_t;
struct ushort4_t { ushort_t x, y, z, w; };
typedef __attribute__((ext_vector_type(8))) short bf16x8;   // 8 bf16 (4 VGPRs)
typedef __attribute__((ext_vector_type(4))) float f32x4;    // MFMA acc

__device__ __forceinline__ float bf2f(ushort_t u) {
    return __uint_as_float(((unsigned int)u) << 16);
}
__device__ __forceinline__ short f2bf_s(float v) {
    __hip_bfloat16 t = __float2bfloat16(v);
    return *(short*)&t;
}
__device__ __forceinline__ unsigned int pack2(float a, float b) {
    return ((unsigned int)(ushort_t)f2bf_s(b) << 16) | (ushort_t)f2bf_s(a);
}

// Device-wide spin barrier. SAFE ONLY because grid=512 with launch_bounds(256,2)
// guarantees 2 blocks/CU x 256 CU = all 512 blocks co-resident.
// t0: release fence (wb L2) -> agent-scope arrive -> acquire spin -> acquire fence (inv L1/L2).
// s_sleep backoff keeps spin atomics ~0.2G/s (vs 24G/s count-atomic budget).
__device__ __forceinline__ void grid_barrier(int* bar, int epoch, int nb) {
    __syncthreads();
    if (threadIdx.x == 0) {
        __threadfence();
        __hip_atomic_fetch_add(bar, 1, __ATOMIC_RELEASE, __HIP_MEMORY_SCOPE_AGENT);
        while (__hip_atomic_load(bar, __ATOMIC_ACQUIRE, __HIP_MEMORY_SCOPE_AGENT) < epoch * nb)
            __builtin_amdgcn_s_sleep(100);
        __threadfence();
    }
    __syncthreads();
}

// ---------------- MEGAKERNEL ----------------
// phase 1: gemm1 (odd blocks) || count+rank (even blocks)   [count's ~70us atomic floor hides gemm1]
// phase 2: scan_partial (padded counts) + dinv              [after barrier 1]
// phase 3: scan_write: row_start + {0,0} pad records        [after barrier 2]
// phase 4: fill pack records {src, norm}                    [after barrier 3]
__global__ __launch_bounds__(256, 2) void megakernel(
        const float* __restrict__ x, const float* __restrict__ W,
        unsigned int* __restrict__ h,
        const int* __restrict__ src, const int* __restrict__ dst,
        int* __restrict__ cnt, int* __restrict__ rank,
        float* __restrict__ dinv, int* __restrict__ bsum,
        int* __restrict__ row_start, int2* __restrict__ pack,
        int* __restrict__ bar,
        int N, int E, int NT, int S) {
    const int bid = blockIdx.x;
    const int tid = threadIdx.x;
    const int NB  = 512;

    // ================= phase 1 =================
    if (bid & 1) {
        // ---- GEMM1 role ----
        const int lane = tid & 63;
        const int m    = lane & 15;
        const int quad = lane >> 4;
        const int gw   = (bid >> 1) * 4 + (tid >> 6);
        const int NW   = 1024;                  // 256 blocks x 4 waves

        bf16x8 a[8][4];                         // 8 col-tiles x 4 k-chunks
        #pragma unroll
        for (int ct = 0; ct < 8; ++ct)
            #pragma unroll
            for (int kc = 0; kc < 4; ++kc)
                #pragma unroll
                for (int j = 0; j < 8; ++j)
                    a[ct][kc][j] = f2bf_s(W[(size_t)(kc * 32 + quad * 8 + j) * HID_DIM + ct * 16 + m]);

        for (int t = gw; t < NT; t += NW) {
            const int n0 = t * 16;
            int node = n0 + m; if (node >= N) node = N - 1;
            const float* xr = x + (size_t)node * IN_DIM + quad * 8;
            f32x4 acc[8];
            #pragma unroll
            for (int ct = 0; ct < 8; ++ct) acc[ct] = (f32x4){0.f, 0.f, 0.f, 0.f};
            #pragma unroll
            for (int kc = 0; kc < 4; ++kc) {
                const float4 v0 = *(const float4*)(xr + kc * 32);
                const float4 v1 = *(const float4*)(xr + kc * 32 + 4);
                bf16x8 b;
                b[0] = f2bf_s(v0.x); b[1] = f2bf_s(v0.y); b[2] = f2bf_s(v0.z); b[3] = f2bf_s(v0.w);
                b[4] = f2bf_s(v1.x); b[5] = f2bf_s(v1.y); b[6] = f2bf_s(v1.z); b[7] = f2bf_s(v1.w);
                #pragma unroll
                for (int ct = 0; ct < 8; ++ct)
                    acc[ct] = __builtin_amdgcn_mfma_f32_16x16x32_bf16(a[ct][kc], b, acc[ct], 0, 0, 0);
            }
            if (n0 + m < N) {
                unsigned int* o = h + (size_t)(n0 + m) * (HID_DIM / 2) + quad * 2;
                #pragma unroll
                for (int ct = 0; ct < 8; ++ct) {
                    uint2 pv;
                    pv.x = pack2(acc[ct][0], acc[ct][1]);
                    pv.y = pack2(acc[ct][2], acc[ct][3]);
                    *(uint2*)(o + ct * 8) = pv;
                }
            }
        }
    } else {
        // ---- count + rank role ----
        const int ct = (bid >> 1) * 256 + tid;
        const int CT = 256 * 256;
        const int nq = E >> 2;
        const int4* d4 = (const int4*)dst;
        for (int q = ct; q < nq; q += CT) {
            const int4 d = d4[q];
            int4 r;
            r.x = atomicAdd(&cnt[d.x], 1);
            r.y = atomicAdd(&cnt[d.y], 1);
            r.z = atomicAdd(&cnt[d.z], 1);
            r.w = atomicAdd(&cnt[d.w], 1);
            ((int4*)rank)[q] = r;
        }
        for (int e = (nq << 2) + ct; e < E; e += CT)
            rank[e] = atomicAdd(&cnt[dst[e]], 1);
    }

    grid_barrier(bar, 1, NB);

    // ================= phase 2: scan_partial + dinv =================
    if (bid < S) {
        __shared__ int wsum2[4];
        const int base = bid * 2048 + tid * 8;
        int s = 0;
        #pragma unroll
        for (int i = 0; i < 8; ++i) {
            if (base + i < N) {
                const int c = cnt[base + i];
                dinv[base + i] = rsqrtf((float)(c + 1));   // +1 self loop
                s += (c + 3) & ~3;
            }
        }
        #pragma unroll
        for (int off = 32; off > 0; off >>= 1) s += __shfl_down(s, off);
        const int lane = tid & 63, w = tid >> 6;
        if (lane == 0) wsum2[w] = s;
        __syncthreads();
        if (tid == 0) bsum[bid] = wsum2[0] + wsum2[1] + wsum2[2] + wsum2[3];
    }

    grid_barrier(bar, 2, NB);

    // ================= phase 3: scan_write (row_start + pad records) =================
    if (bid < S) {
        __shared__ int wsum3[4];
        __shared__ int blockoff;
        if (tid < 64) {
            int a = 0;
            for (int idx = tid; idx < bid; idx += 64) a += bsum[idx];
            #pragma unroll
            for (int off = 32; off > 0; off >>= 1) a += __shfl_down(a, off);
            if (tid == 0) blockoff = a;
        }
        const int base = bid * 2048 + tid * 8;
        int c[8], v[8];
        #pragma unroll
        for (int i = 0; i < 8; ++i) {
            c[i] = (base + i < N) ? cnt[base + i] : 0;
            v[i] = (c[i] + 3) & ~3;
        }
        int s = v[0] + v[1] + v[2] + v[3] + v[4] + v[5] + v[6] + v[7];
        const int lane = tid & 63, w = tid >> 6;
        int incl = s;
        #pragma unroll
        for (int off = 1; off < 64; off <<= 1) {
            int u = __shfl_up(incl, off);
            if (lane >= off) incl += u;
        }
        if (lane == 63) wsum3[w] = incl;
        __syncthreads();
        int woff = 0;
        for (int i = 0; i < w; ++i) woff += wsum3[i];
        int run = blockoff + woff + (incl - s);
        const int2 zr = {0, 0};
        #pragma unroll
        for (int i = 0; i < 8; ++i) {
            if (base + i < N) {
                row_start[base + i] = run;
                for (int p = c[i]; p < v[i]; ++p) pack[run + p] = zr;   // pad: src=0, norm=0
                run += v[i];
            }
        }
    }

    grid_barrier(bar, 3, NB);

    // ================= phase 4: fill pack records {src, norm} =================
    {
        const int gtid = bid * 256 + tid;
        const int GT = NB * 256;
        const int nq = E >> 2;
        for (int q = gtid; q < nq; q += GT) {
            const int4 s = ((const int4*)src)[q];
            const int4 d = ((const int4*)dst)[q];
            const int4 r = ((const int4*)rank)[q];
            int2 p;
            p.x = s.x; p.y = __float_as_int(dinv[s.x] * dinv[d.x]);
            pack[row_start[d.x] + r.x] = p;
            p.x = s.y; p.y = __float_as_int(dinv[s.y] * dinv[d.y]);
            pack[row_start[d.y] + r.y] = p;
            p.x = s.z; p.y = __float_as_int(dinv[s.z] * dinv[d.z]);
            pack[row_start[d.z] + r.z] = p;
            p.x = s.w; p.y = __float_as_int(dinv[s.w] * dinv[d.w]);
            pack[row_start[d.w] + r.w] = p;
        }
        if (gtid == 0) {   // tail (E not multiple of 4)
            for (int e = nq << 2; e < E; ++e) {
                int2 p;
                p.x = src[e]; p.y = __float_as_int(dinv[src[e]] * dinv[dst[e]]);
                pack[row_start[dst[e]] + rank[e]] = p;
            }
        }
    }
}

// ---------------- GEMM2 (MFMA): h2[N,64](bf16) = agg_relu[N,128](bf16) @ W2[128,64] ----------------
__global__ __launch_bounds__(256) void gemm2_mfma(
        const ushort_t* __restrict__ agg,
        const float* __restrict__ W2, unsigned int* __restrict__ h2,
        int N, int NT, int NW) {
    const int tid  = threadIdx.x;
    const int lane = tid & 63;
    const int m    = lane & 15;
    const int quad = lane >> 4;
    const int gw   = blockIdx.x * 4 + (tid >> 6);

    bf16x8 a[4][4];                         // 4 col-tiles x 4 k-chunks
    #pragma unroll
    for (int ct = 0; ct < 4; ++ct)
        #pragma unroll
        for (int kc = 0; kc < 4; ++kc)
            #pragma unroll
            for (int j = 0; j < 8; ++j)
                a[ct][kc][j] = f2bf_s(W2[(size_t)(kc * 32 + quad * 8 + j) * OUT_DIM + ct * 16 + m]);

    for (int t = gw; t < NT; t += NW) {
        const int n0 = t * 16;
        int node = n0 + m; if (node >= N) node = N - 1;
        const ushort_t* ar = agg + (size_t)node * HID_DIM + quad * 8;
        f32x4 acc[4];
        #pragma unroll
        for (int ct = 0; ct < 4; ++ct) acc[ct] = (f32x4){0.f, 0.f, 0.f, 0.f};
        #pragma unroll
        for (int kc = 0; kc < 4; ++kc) {
            const bf16x8 b = *(const bf16x8*)(ar + kc * 32);
            #pragma unroll
            for (int ct = 0; ct < 4; ++ct)
                acc[ct] = __builtin_amdgcn_mfma_f32_16x16x32_bf16(a[ct][kc], b, acc[ct], 0, 0, 0);
        }
        if (n0 + m < N) {
            unsigned int* o = h2 + (size_t)(n0 + m) * (OUT_DIM / 2) + quad * 2;
            #pragma unroll
            for (int ct = 0; ct < 4; ++ct) {
                uint2 pv;
                pv.x = pack2(acc[ct][0], acc[ct][1]);
                pv.y = pack2(acc[ct][2], acc[ct][3]);
                *(uint2*)(o + ct * 8) = pv;
            }
        }
    }
}

// ---------------- gather aggregation over {src, norm} records, 8 records/iter ----------------
// pad records are {0, 0.0f} -> contribute nothing. bias pre-added (commutes), relu post-loop.
#define GREC(P, HI) do { \
        const ushort4_t v = *(const ushort4_t*)(h + (size_t)(HI ? (P).z : (P).x) * D + f); \
        const float n = __int_as_float(HI ? (P).w : (P).y); \
        acc.x += bf2f(v.x) * n; acc.y += bf2f(v.y) * n; \
        acc.z += bf2f(v.z) * n; acc.w += bf2f(v.w) * n; \
    } while (0)

template<int D, bool BF16_OUT, bool RELU>
__global__ void gather_bf16(const ushort_t* __restrict__ h, const int2* __restrict__ pack,
                            const int* __restrict__ row_start, const int* __restrict__ cnt,
                            const float* __restrict__ dinv, const float* __restrict__ bias,
                            int N, void* __restrict__ outv) {
    const int TPN = D / 4;
    const int NPB = 256 / TPN;
    const int t = threadIdx.x;
    const int node = blockIdx.x * NPB + t / TPN;
    if (node >= N) return;
    const int f = (t & (TPN - 1)) * 4;
    const float dd = dinv[node];

    const ushort4_t self = *(const ushort4_t*)(h + (size_t)node * D + f);
    const float sn = dd * dd;
    float4 acc;
    acc.x = bf2f(self.x) * sn; acc.y = bf2f(self.y) * sn;
    acc.z = bf2f(self.z) * sn; acc.w = bf2f(self.w) * sn;
    const float4 bv = *(const float4*)(bias + f);
    acc.x += bv.x; acc.y += bv.y; acc.z += bv.z; acc.w += bv.w;

    const int2* pk = pack + row_start[node];       // 32B-aligned (start % 4 == 0)
    const int cpad = (cnt[node] + 3) & ~3;
    int e = 0;
    for (; e + 8 <= cpad; e += 8) {                // 8 records in flight (4 int4 + 8 row loads)
        const int4 p0 = *(const int4*)(pk + e);
        const int4 p1 = *(const int4*)(pk + e + 2);
        const int4 p2 = *(const int4*)(pk + e + 4);
        const int4 p3 = *(const int4*)(pk + e + 6);
        GREC(p0, 0); GREC(p0, 1);
        GREC(p1, 0); GREC(p1, 1);
        GREC(p2, 0); GREC(p2, 1);
        GREC(p3, 0); GREC(p3, 1);
    }
    if (e < cpad) {                                // one remaining 4-record quad
        const int4 p0 = *(const int4*)(pk + e);
        const int4 p1 = *(const int4*)(pk + e + 2);
        GREC(p0, 0); GREC(p0, 1);
        GREC(p1, 0); GREC(p1, 1);
    }
    if (RELU) {
        acc.x = fmaxf(acc.x, 0.f); acc.y = fmaxf(acc.y, 0.f);
        acc.z = fmaxf(acc.z, 0.f); acc.w = fmaxf(acc.w, 0.f);
    }
    if (BF16_OUT) {
        unsigned int* out = (unsigned int*)outv;
        uint2 pv;
        pv.x = pack2(acc.x, acc.y);
        pv.y = pack2(acc.z, acc.w);
        *(uint2*)(out + ((size_t)node * D + f) / 2) = pv;
    } else {
        float* out = (float*)outv;
        *(float4*)(out + (size_t)node * D + f) = acc;
    }
}

extern "C" void kernel_launch(void* const* d_in, const int* in_sizes, int n_in,
                              void* d_out, int out_size, void* d_ws, size_t ws_size,
                              hipStream_t stream) {
    const float* x   = (const float*)d_in[0];
    const int*   ei  = (const int*)  d_in[1];
    const float* W1  = (const float*)d_in[2];
    const float* b1  = (const float*)d_in[3];
    const float* W2  = (const float*)d_in[4];
    const float* b2  = (const float*)d_in[5];
    float* out = (float*)d_out;

    const int N = in_sizes[0] / IN_DIM;     // 100000
    const int E = in_sizes[1] / 2;          // 1600000
    const int* src = ei;                    // edge_index[0]
    const int* dst = ei + E;                // edge_index[1]

    // workspace layout (4B units):
    // dinv[N] | cnt[N] | bar[16] | row_start[N] | bsum[1024] | align | pack[E+4N] int2
    // | h1[N*64] u32 (bf16 h1, reused as h2) | agg1[N*64] u32 (bf16; rank aliases it)
    const int PACK_CAP = E + 4 * N;
    float* dinv      = (float*)d_ws;
    int*   cnt       = (int*)(dinv + N);
    int*   bar       = cnt + N;             // 16 ints, zeroed with cnt
    int*   row_start = bar + 16;
    int*   bsum      = row_start + N;
    size_t off       = (size_t)(3 * N + 16 + 1024);
    off = (off + 3) & ~(size_t)3;           // 16B-align pack
    int2*  pack      = (int2*)((int*)d_ws + off);
    unsigned int* h1 = (unsigned int*)(pack + PACK_CAP);
    unsigned int* agg1 = h1 + (size_t)N * (HID_DIM / 2);
    int*   rank      = (int*)agg1;          // alive only until fill phase (E <= N*64)
    unsigned int* h2 = h1;                  // reuse after gather128

    const int S = (N + 2047) / 2048;        // scan blocks (49 <= 512)
    const int NT = (N + 15) / 16;           // 16-node MFMA tiles

    // 1) megakernel: count+gemm1 || -> scan -> row_start/pads -> fill  (3 internal barriers)
    hipMemsetAsync(cnt, 0, ((size_t)N + 16) * sizeof(int), stream);   // cnt + bar
    megakernel<<<512, 256, 0, stream>>>(x, W1, h1, src, dst, cnt, rank,
                                        dinv, bsum, row_start, pack, bar, N, E, NT, S);

    // 2) agg1 = relu(gather(h1) + b1)  (bf16 out; overwrites rank)
    gather_bf16<HID_DIM, true, true><<<(N + 7) / 8, 256, 0, stream>>>(
        (const ushort_t*)h1, pack, row_start, cnt, dinv, b1, N, (void*)agg1);

    // 3) h2 = agg1 @ W2  (bf16 out, MFMA, raw b-frag loads)
    gemm2_mfma<<<768, 256, 0, stream>>>(
        (const ushort_t*)agg1, W2, h2, N, NT, 768 * 4);

    // 4) out = b2 + gather(h2)  (f32 out)
    gather_bf16<OUT_DIM, false, false><<<(N + 15) / 16, 256, 0, stream>>>(
        (const ushort_t*)h2, pack, row_start, cnt, dinv, b2, N, (void*)out);
}

// Round 6
// 336.324 us; speedup vs baseline: 1.7298x; 1.7298x over previous
//
#include <hip/hip_runtime.h>
#include <hip/hip_bf16.h>

#define IN_DIM  128
#define HID_DIM 128
#define OUT_DIM 64
#define NSHADOW 8

typedef unsigned short ushort_t;
struct ushort4_t { ushort_t x, y, z, w; };
typedef __attribute__((ext_vector_type(8))) short bf16x8;   // 8 bf16 (4 VGPRs)
typedef __attribute__((ext_vector_type(4))) float f32x4;    // MFMA acc

__device__ __forceinline__ float bf2f(ushort_t u) {
    return __uint_as_float(((unsigned int)u) << 16);
}
__device__ __forceinline__ short f2bf_s(float v) {
    __hip_bfloat16 t = __float2bfloat16(v);
    return *(short*)&t;
}
__device__ __forceinline__ unsigned int pack2(float a, float b) {
    return ((unsigned int)(ushort_t)f2bf_s(b) << 16) | (ushort_t)f2bf_s(a);
}

// ---------------- FUSED: gemm1 (odd blocks) || count+rank (even blocks) ----------------
// count role was per-cacheline-serialization-bound (~24G atomics/s, same dur at any grid).
// 8 shadow cnt arrays cut same-line collisions 8x; shadow id is reproducible from quad id.
__global__ __launch_bounds__(256, 2) void fused_gemm1_count(
        const float* __restrict__ x, const float* __restrict__ W,
        unsigned int* __restrict__ h,
        const int* __restrict__ dst, int* __restrict__ scnt, int* __restrict__ rank,
        int N, int E, int NT) {
    const int bid = blockIdx.x;
    const int tid = threadIdx.x;

    if (bid & 1) {
        // ---- GEMM1 role ----
        const int lane = tid & 63;
        const int m    = lane & 15;
        const int quad = lane >> 4;
        const int gw   = (bid >> 1) * 4 + (tid >> 6);
        const int NW   = 1024;                  // 256 blocks x 4 waves

        bf16x8 a[8][4];                         // 8 col-tiles x 4 k-chunks
        #pragma unroll
        for (int ct = 0; ct < 8; ++ct)
            #pragma unroll
            for (int kc = 0; kc < 4; ++kc)
                #pragma unroll
                for (int j = 0; j < 8; ++j)
                    a[ct][kc][j] = f2bf_s(W[(size_t)(kc * 32 + quad * 8 + j) * HID_DIM + ct * 16 + m]);

        for (int t = gw; t < NT; t += NW) {
            const int n0 = t * 16;
            int node = n0 + m; if (node >= N) node = N - 1;
            const float* xr = x + (size_t)node * IN_DIM + quad * 8;
            f32x4 acc[8];
            #pragma unroll
            for (int ct = 0; ct < 8; ++ct) acc[ct] = (f32x4){0.f, 0.f, 0.f, 0.f};
            #pragma unroll
            for (int kc = 0; kc < 4; ++kc) {
                const float4 v0 = *(const float4*)(xr + kc * 32);
                const float4 v1 = *(const float4*)(xr + kc * 32 + 4);
                bf16x8 b;
                b[0] = f2bf_s(v0.x); b[1] = f2bf_s(v0.y); b[2] = f2bf_s(v0.z); b[3] = f2bf_s(v0.w);
                b[4] = f2bf_s(v1.x); b[5] = f2bf_s(v1.y); b[6] = f2bf_s(v1.z); b[7] = f2bf_s(v1.w);
                #pragma unroll
                for (int ct = 0; ct < 8; ++ct)
                    acc[ct] = __builtin_amdgcn_mfma_f32_16x16x32_bf16(a[ct][kc], b, acc[ct], 0, 0, 0);
            }
            if (n0 + m < N) {
                unsigned int* o = h + (size_t)(n0 + m) * (HID_DIM / 2) + quad * 2;
                #pragma unroll
                for (int ct = 0; ct < 8; ++ct) {
                    uint2 pv;
                    pv.x = pack2(acc[ct][0], acc[ct][1]);
                    pv.y = pack2(acc[ct][2], acc[ct][3]);
                    *(uint2*)(o + ct * 8) = pv;
                }
            }
        }
    } else {
        // ---- count + rank role (shadowed) ----
        const int ct = (bid >> 1) * 256 + tid;
        const int CT = 256 * 256;
        const int sh = (ct >> 8) & (NSHADOW - 1);     // == ((q & (CT-1)) >> 8) & 7
        int* __restrict__ mycnt = scnt + (size_t)sh * N;
        const int nq = E >> 2;
        const int4* d4 = (const int4*)dst;
        for (int q = ct; q < nq; q += CT) {
            const int4 d = d4[q];
            int4 r;
            r.x = atomicAdd(&mycnt[d.x], 1);
            r.y = atomicAdd(&mycnt[d.y], 1);
            r.z = atomicAdd(&mycnt[d.z], 1);
            r.w = atomicAdd(&mycnt[d.w], 1);
            ((int4*)rank)[q] = r;
        }
        for (int e = (nq << 2) + ct; e < E; e += CT) {
            const int sh2 = ((e - (nq << 2)) >> 8) & (NSHADOW - 1);
            rank[e] = atomicAdd(&scnt[(size_t)sh2 * N + dst[e]], 1);
        }
    }
}

// ---------------- scan: sum shadows -> cnt, dinv, per-block padded sums ----------------
__global__ void scan_partial(const int* __restrict__ scnt, int* __restrict__ cnt,
                             int* __restrict__ bsum, float* __restrict__ dinv, int N) {
    __shared__ int wsum[4];
    const int t = threadIdx.x;
    const int base = blockIdx.x * 2048 + t * 8;
    int s = 0;
    #pragma unroll
    for (int i = 0; i < 8; ++i) {
        if (base + i < N) {
            int c = 0;
            #pragma unroll
            for (int sh = 0; sh < NSHADOW; ++sh) c += scnt[(size_t)sh * N + base + i];
            cnt[base + i] = c;
            dinv[base + i] = rsqrtf((float)(c + 1));   // +1 self loop
            s += (c + 3) & ~3;
        }
    }
    #pragma unroll
    for (int off = 32; off > 0; off >>= 1) s += __shfl_down(s, off);
    const int lane = t & 63, w = t >> 6;
    if (lane == 0) wsum[w] = s;
    __syncthreads();
    if (t == 0) bsum[blockIdx.x] = wsum[0] + wsum[1] + wsum[2] + wsum[3];
}

// scan_write: row_start (record units, x4) + {0,0} pad records + per-shadow bases sb[8][N].
// sb[sh][i] = row_start[i] + sum_{sh'<sh} scnt[sh'][i]  (so fill uses sb[sh][d] + local rank).
__global__ void scan_write(const int* __restrict__ cnt, const int* __restrict__ scnt,
                           const int* __restrict__ bsum,
                           int* __restrict__ row_start, int* __restrict__ sb,
                           int2* __restrict__ pack, int N) {
    __shared__ int wsum[4];
    __shared__ int blockoff;
    const int t = threadIdx.x;
    if (t < 64) {
        int a = 0;
        for (int idx = t; idx < blockIdx.x; idx += 64) a += bsum[idx];
        #pragma unroll
        for (int off = 32; off > 0; off >>= 1) a += __shfl_down(a, off);
        if (t == 0) blockoff = a;
    }
    const int base = blockIdx.x * 2048 + t * 8;
    int c[8], v[8];
    #pragma unroll
    for (int i = 0; i < 8; ++i) {
        c[i] = (base + i < N) ? cnt[base + i] : 0;
        v[i] = (c[i] + 3) & ~3;
    }
    int s = v[0] + v[1] + v[2] + v[3] + v[4] + v[5] + v[6] + v[7];
    const int lane = t & 63, w = t >> 6;
    int incl = s;
    #pragma unroll
    for (int off = 1; off < 64; off <<= 1) {
        int u = __shfl_up(incl, off);
        if (lane >= off) incl += u;
    }
    if (lane == 63) wsum[w] = incl;
    __syncthreads();
    int woff = 0;
    for (int i = 0; i < w; ++i) woff += wsum[i];
    int run = blockoff + woff + (incl - s);
    const int2 zr = {0, 0};
    #pragma unroll
    for (int i = 0; i < 8; ++i) {
        if (base + i < N) {
            row_start[base + i] = run;
            int a = run;
            #pragma unroll
            for (int sh = 0; sh < NSHADOW; ++sh) {
                sb[(size_t)sh * N + base + i] = a;
                a += scnt[(size_t)sh * N + base + i];
            }
            for (int p = c[i]; p < v[i]; ++p) pack[run + p] = zr;   // pad: src=0, norm=0
            run += v[i];
        }
    }
}

// ---------------- fill packed CSR records {src, norm} (8B), no atomics, x4-vectorized ----------------
// Slot = sb[shadow(q)][dst] + local_rank, where shadow(q) reproduces the count role's mapping.
__global__ void fill_pack4(const int* __restrict__ src, const int* __restrict__ dst,
                           const int* __restrict__ rank, const int* __restrict__ sb,
                           const float* __restrict__ dinv, int N, int E, int2* __restrict__ pack) {
    const int q = blockIdx.x * blockDim.x + threadIdx.x;
    const int CT = 256 * 256;
    const int nq = E >> 2;
    if (q < nq) {
        const int sh = ((q & (CT - 1)) >> 8) & (NSHADOW - 1);
        const int* __restrict__ sbs = sb + (size_t)sh * N;
        const int4 s = ((const int4*)src)[q];
        const int4 d = ((const int4*)dst)[q];
        const int4 r = ((const int4*)rank)[q];
        int2 p;
        p.x = s.x; p.y = __float_as_int(dinv[s.x] * dinv[d.x]);
        pack[sbs[d.x] + r.x] = p;
        p.x = s.y; p.y = __float_as_int(dinv[s.y] * dinv[d.y]);
        pack[sbs[d.y] + r.y] = p;
        p.x = s.z; p.y = __float_as_int(dinv[s.z] * dinv[d.z]);
        pack[sbs[d.z] + r.z] = p;
        p.x = s.w; p.y = __float_as_int(dinv[s.w] * dinv[d.w]);
        pack[sbs[d.w] + r.w] = p;
    }
    if (q == 0) {   // tail (E not multiple of 4)
        for (int e = nq << 2; e < E; ++e) {
            const int sh = ((e - (nq << 2)) >> 8) & (NSHADOW - 1);
            int2 p;
            p.x = src[e]; p.y = __float_as_int(dinv[src[e]] * dinv[dst[e]]);
            pack[sb[(size_t)sh * N + dst[e]] + rank[e]] = p;
        }
    }
}

// ---------------- GEMM2 (MFMA): h2[N,64](bf16) = agg_relu[N,128](bf16) @ W2[128,64] ----------------
__global__ __launch_bounds__(256) void gemm2_mfma(
        const ushort_t* __restrict__ agg,
        const float* __restrict__ W2, unsigned int* __restrict__ h2,
        int N, int NT, int NW) {
    const int tid  = threadIdx.x;
    const int lane = tid & 63;
    const int m    = lane & 15;
    const int quad = lane >> 4;
    const int gw   = blockIdx.x * 4 + (tid >> 6);

    bf16x8 a[4][4];                         // 4 col-tiles x 4 k-chunks
    #pragma unroll
    for (int ct = 0; ct < 4; ++ct)
        #pragma unroll
        for (int kc = 0; kc < 4; ++kc)
            #pragma unroll
            for (int j = 0; j < 8; ++j)
                a[ct][kc][j] = f2bf_s(W2[(size_t)(kc * 32 + quad * 8 + j) * OUT_DIM + ct * 16 + m]);

    for (int t = gw; t < NT; t += NW) {
        const int n0 = t * 16;
        int node = n0 + m; if (node >= N) node = N - 1;
        const ushort_t* ar = agg + (size_t)node * HID_DIM + quad * 8;
        f32x4 acc[4];
        #pragma unroll
        for (int ct = 0; ct < 4; ++ct) acc[ct] = (f32x4){0.f, 0.f, 0.f, 0.f};
        #pragma unroll
        for (int kc = 0; kc < 4; ++kc) {
            const bf16x8 b = *(const bf16x8*)(ar + kc * 32);
            #pragma unroll
            for (int ct = 0; ct < 4; ++ct)
                acc[ct] = __builtin_amdgcn_mfma_f32_16x16x32_bf16(a[ct][kc], b, acc[ct], 0, 0, 0);
        }
        if (n0 + m < N) {
            unsigned int* o = h2 + (size_t)(n0 + m) * (OUT_DIM / 2) + quad * 2;
            #pragma unroll
            for (int ct = 0; ct < 4; ++ct) {
                uint2 pv;
                pv.x = pack2(acc[ct][0], acc[ct][1]);
                pv.y = pack2(acc[ct][2], acc[ct][3]);
                *(uint2*)(o + ct * 8) = pv;
            }
        }
    }
}

// ---------------- gather aggregation over {src, norm} records, 8 records/iter ----------------
// pad records are {0, 0.0f} -> contribute nothing. bias pre-added (commutes), relu post-loop.
#define GREC(P, HI) do { \
        const ushort4_t v = *(const ushort4_t*)(h + (size_t)(HI ? (P).z : (P).x) * D + f); \
        const float n = __int_as_float(HI ? (P).w : (P).y); \
        acc.x += bf2f(v.x) * n; acc.y += bf2f(v.y) * n; \
        acc.z += bf2f(v.z) * n; acc.w += bf2f(v.w) * n; \
    } while (0)

template<int D, bool BF16_OUT, bool RELU>
__global__ void gather_bf16(const ushort_t* __restrict__ h, const int2* __restrict__ pack,
                            const int* __restrict__ row_start, const int* __restrict__ cnt,
                            const float* __restrict__ dinv, const float* __restrict__ bias,
                            int N, void* __restrict__ outv) {
    const int TPN = D / 4;
    const int NPB = 256 / TPN;
    const int t = threadIdx.x;
    const int node = blockIdx.x * NPB + t / TPN;
    if (node >= N) return;
    const int f = (t & (TPN - 1)) * 4;
    const float dd = dinv[node];

    const ushort4_t self = *(const ushort4_t*)(h + (size_t)node * D + f);
    const float sn = dd * dd;
    float4 acc;
    acc.x = bf2f(self.x) * sn; acc.y = bf2f(self.y) * sn;
    acc.z = bf2f(self.z) * sn; acc.w = bf2f(self.w) * sn;
    const float4 bv = *(const float4*)(bias + f);
    acc.x += bv.x; acc.y += bv.y; acc.z += bv.z; acc.w += bv.w;

    const int2* pk = pack + row_start[node];       // 32B-aligned (start % 4 == 0)
    const int cpad = (cnt[node] + 3) & ~3;
    int e = 0;
    for (; e + 8 <= cpad; e += 8) {                // 8 records in flight (4 int4 + 8 row loads)
        const int4 p0 = *(const int4*)(pk + e);
        const int4 p1 = *(const int4*)(pk + e + 2);
        const int4 p2 = *(const int4*)(pk + e + 4);
        const int4 p3 = *(const int4*)(pk + e + 6);
        GREC(p0, 0); GREC(p0, 1);
        GREC(p1, 0); GREC(p1, 1);
        GREC(p2, 0); GREC(p2, 1);
        GREC(p3, 0); GREC(p3, 1);
    }
    if (e < cpad) {                                // one remaining 4-record quad
        const int4 p0 = *(const int4*)(pk + e);
        const int4 p1 = *(const int4*)(pk + e + 2);
        GREC(p0, 0); GREC(p0, 1);
        GREC(p1, 0); GREC(p1, 1);
    }
    if (RELU) {
        acc.x = fmaxf(acc.x, 0.f); acc.y = fmaxf(acc.y, 0.f);
        acc.z = fmaxf(acc.z, 0.f); acc.w = fmaxf(acc.w, 0.f);
    }
    if (BF16_OUT) {
        unsigned int* out = (unsigned int*)outv;
        uint2 pv;
        pv.x = pack2(acc.x, acc.y);
        pv.y = pack2(acc.z, acc.w);
        *(uint2*)(out + ((size_t)node * D + f) / 2) = pv;
    } else {
        float* out = (float*)outv;
        *(float4*)(out + (size_t)node * D + f) = acc;
    }
}

extern "C" void kernel_launch(void* const* d_in, const int* in_sizes, int n_in,
                              void* d_out, int out_size, void* d_ws, size_t ws_size,
                              hipStream_t stream) {
    const float* x   = (const float*)d_in[0];
    const int*   ei  = (const int*)  d_in[1];
    const float* W1  = (const float*)d_in[2];
    const float* b1  = (const float*)d_in[3];
    const float* W2  = (const float*)d_in[4];
    const float* b2  = (const float*)d_in[5];
    float* out = (float*)d_out;

    const int N = in_sizes[0] / IN_DIM;     // 100000
    const int E = in_sizes[1] / 2;          // 1600000
    const int* src = ei;                    // edge_index[0]
    const int* dst = ei + E;                // edge_index[1]

    // workspace layout (4B units):
    // dinv[N] | cnt[N] | row_start[N] | bsum[1024] | scnt[8N] | sb[8N] | align | pack[E+4N] int2
    // | h1[N*64] u32 (bf16 h1, reused as h2) | agg1[N*64] u32 (bf16; rank aliases it)
    const int PACK_CAP = E + 4 * N;
    float* dinv      = (float*)d_ws;
    int*   cnt       = (int*)(dinv + N);
    int*   row_start = cnt + N;
    int*   bsum      = row_start + N;
    int*   scnt      = bsum + 1024;
    int*   sb        = scnt + (size_t)NSHADOW * N;
    size_t off       = (size_t)(3 * N + 1024) + (size_t)2 * NSHADOW * N;
    off = (off + 3) & ~(size_t)3;           // 16B-align pack
    int2*  pack      = (int2*)((int*)d_ws + off);
    unsigned int* h1 = (unsigned int*)(pack + PACK_CAP);
    unsigned int* agg1 = h1 + (size_t)N * (HID_DIM / 2);
    int*   rank      = (int*)agg1;          // alive only until fill_pack (E <= N*64)
    unsigned int* h2 = h1;                  // reuse after gather128

    const int B = 256;
    const int S = (N + 2047) / 2048;        // scan blocks
    const int NT = (N + 15) / 16;           // 16-node MFMA tiles

    // 1) shadowed CSR counts + rank, fused with GEMM1
    hipMemsetAsync(scnt, 0, (size_t)NSHADOW * N * sizeof(int), stream);
    fused_gemm1_count<<<512, 256, 0, stream>>>(x, W1, h1, dst, scnt, rank, N, E, NT);

    // 2) scan: shadows -> cnt + dinv + block sums; then row_start + sb + pad records
    scan_partial<<<S, 256, 0, stream>>>(scnt, cnt, bsum, dinv, N);
    scan_write<<<S, 256, 0, stream>>>(cnt, scnt, bsum, row_start, sb, pack, N);

    // 3) fill packed CSR records {src, norm} at sb[shadow][dst] + local_rank
    fill_pack4<<<((E >> 2) + B - 1) / B, B, 0, stream>>>(src, dst, rank, sb, dinv, N, E, pack);

    // 4) agg1 = relu(gather(h1) + b1)  (bf16 out; overwrites rank)
    gather_bf16<HID_DIM, true, true><<<(N + 7) / 8, 256, 0, stream>>>(
        (const ushort_t*)h1, pack, row_start, cnt, dinv, b1, N, (void*)agg1);

    // 5) h2 = agg1 @ W2  (bf16 out, MFMA, raw b-frag loads)
    gemm2_mfma<<<768, 256, 0, stream>>>(
        (const ushort_t*)agg1, W2, h2, N, NT, 768 * 4);

    // 6) out = b2 + gather(h2)  (f32 out)
    gather_bf16<OUT_DIM, false, false><<<(N + 15) / 16, 256, 0, stream>>>(
        (const ushort_t*)h2, pack, row_start, cnt, dinv, b2, N, (void*)out);
}

// Round 8
// 317.935 us; speedup vs baseline: 1.8299x; 1.0578x over previous
//
#include <hip/hip_runtime.h>
#include <hip/hip_bf16.h>

#define IN_DIM  128
#define HID_DIM 128
#define OUT_DIM 64

typedef unsigned short ushort_t;
struct ushort4_t { ushort_t x, y, z, w; };
typedef __attribute__((ext_vector_type(8))) short bf16x8;   // 8 bf16 (4 VGPRs)
typedef __attribute__((ext_vector_type(4))) float f32x4;    // MFMA acc

__device__ __forceinline__ float bf2f(ushort_t u) {
    return __uint_as_float(((unsigned int)u) << 16);
}
__device__ __forceinline__ short f2bf_s(float v) {
    __hip_bfloat16 t = __float2bfloat16(v);
    return *(short*)&t;
}
__device__ __forceinline__ unsigned int pack2(float a, float b) {
    return ((unsigned int)(ushort_t)f2bf_s(b) << 16) | (ushort_t)f2bf_s(a);
}

// ---------------- FUSED: gemm1 (odd blocks) || count+rank (even blocks) ----------------
// count role is device-atomic-throughput-bound (~24G/s HW ceiling: insensitive to grid size,
// collisions [r6 shadow test], occupancy [r0/r1]) and hides the whole GEMM for free.
__global__ __launch_bounds__(256, 2) void fused_gemm1_count(
        const float* __restrict__ x, const float* __restrict__ W,
        unsigned int* __restrict__ h,
        const int* __restrict__ dst, int* __restrict__ cnt, int* __restrict__ rank,
        int N, int E, int NT) {
    const int bid = blockIdx.x;
    const int tid = threadIdx.x;

    if (bid & 1) {
        // ---- GEMM1 role ----
        const int lane = tid & 63;
        const int m    = lane & 15;
        const int quad = lane >> 4;
        const int gw   = (bid >> 1) * 4 + (tid >> 6);
        const int NW   = 1024;                  // 256 blocks x 4 waves

        bf16x8 a[8][4];                         // 8 col-tiles x 4 k-chunks
        #pragma unroll
        for (int ct = 0; ct < 8; ++ct)
            #pragma unroll
            for (int kc = 0; kc < 4; ++kc)
                #pragma unroll
                for (int j = 0; j < 8; ++j)
                    a[ct][kc][j] = f2bf_s(W[(size_t)(kc * 32 + quad * 8 + j) * HID_DIM + ct * 16 + m]);

        for (int t = gw; t < NT; t += NW) {
            const int n0 = t * 16;
            int node = n0 + m; if (node >= N) node = N - 1;
            const float* xr = x + (size_t)node * IN_DIM + quad * 8;
            f32x4 acc[8];
            #pragma unroll
            for (int ct = 0; ct < 8; ++ct) acc[ct] = (f32x4){0.f, 0.f, 0.f, 0.f};
            #pragma unroll
            for (int kc = 0; kc < 4; ++kc) {
                const float4 v0 = *(const float4*)(xr + kc * 32);
                const float4 v1 = *(const float4*)(xr + kc * 32 + 4);
                bf16x8 b;
                b[0] = f2bf_s(v0.x); b[1] = f2bf_s(v0.y); b[2] = f2bf_s(v0.z); b[3] = f2bf_s(v0.w);
                b[4] = f2bf_s(v1.x); b[5] = f2bf_s(v1.y); b[6] = f2bf_s(v1.z); b[7] = f2bf_s(v1.w);
                #pragma unroll
                for (int ct = 0; ct < 8; ++ct)
                    acc[ct] = __builtin_amdgcn_mfma_f32_16x16x32_bf16(a[ct][kc], b, acc[ct], 0, 0, 0);
            }
            if (n0 + m < N) {
                unsigned int* o = h + (size_t)(n0 + m) * (HID_DIM / 2) + quad * 2;
                #pragma unroll
                for (int ct = 0; ct < 8; ++ct) {
                    uint2 pv;
                    pv.x = pack2(acc[ct][0], acc[ct][1]);
                    pv.y = pack2(acc[ct][2], acc[ct][3]);
                    *(uint2*)(o + ct * 8) = pv;
                }
            }
        }
    } else {
        // ---- count + rank role: 8 atomics in flight per thread ----
        const int ct = (bid >> 1) * 256 + tid;
        const int CT = 256 * 256;
        const int nq8 = E >> 3;                 // pairs of int4
        const int4* d4 = (const int4*)dst;
        for (int q = ct; q < nq8; q += CT) {
            const int4 d0 = d4[2 * q];
            const int4 d1 = d4[2 * q + 1];
            int4 r0, r1;
            r0.x = atomicAdd(&cnt[d0.x], 1);
            r0.y = atomicAdd(&cnt[d0.y], 1);
            r0.z = atomicAdd(&cnt[d0.z], 1);
            r0.w = atomicAdd(&cnt[d0.w], 1);
            r1.x = atomicAdd(&cnt[d1.x], 1);
            r1.y = atomicAdd(&cnt[d1.y], 1);
            r1.z = atomicAdd(&cnt[d1.z], 1);
            r1.w = atomicAdd(&cnt[d1.w], 1);
            ((int4*)rank)[2 * q]     = r0;
            ((int4*)rank)[2 * q + 1] = r1;
        }
        for (int e = (nq8 << 3) + ct; e < E; e += CT)
            rank[e] = atomicAdd(&cnt[dst[e]], 1);
    }
}

// ---------------- scan: per-block sums of PADDED counts ((cnt+3)&~3), dinv folded in ----------------
__global__ void scan_partial(const int* __restrict__ cnt, int* __restrict__ bsum,
                             float* __restrict__ dinv, int N) {
    __shared__ int wsum[4];
    const int t = threadIdx.x;
    const int base = blockIdx.x * 2048 + t * 8;
    int s = 0;
    #pragma unroll
    for (int i = 0; i < 8; ++i) {
        if (base + i < N) {
            const int c = cnt[base + i];
            dinv[base + i] = rsqrtf((float)(c + 1));   // +1 self loop
            s += (c + 3) & ~3;
        }
    }
    #pragma unroll
    for (int off = 32; off > 0; off >>= 1) s += __shfl_down(s, off);
    const int lane = t & 63, w = t >> 6;
    if (lane == 0) wsum[w] = s;
    __syncthreads();
    if (t == 0) bsum[blockIdx.x] = wsum[0] + wsum[1] + wsum[2] + wsum[3];
}

// scan_write: row_start (record units, x4) + {0,0} pad records (<=3/node).
// Block offset computed in-kernel from raw bsum (S tiny) -> no separate scan launch.
__global__ void scan_write(const int* __restrict__ cnt, const int* __restrict__ bsum,
                           int* __restrict__ row_start, int2* __restrict__ pack, int N) {
    __shared__ int wsum[4];
    __shared__ int blockoff;
    const int t = threadIdx.x;
    if (t < 64) {
        int a = 0;
        for (int idx = t; idx < blockIdx.x; idx += 64) a += bsum[idx];
        #pragma unroll
        for (int off = 32; off > 0; off >>= 1) a += __shfl_down(a, off);
        if (t == 0) blockoff = a;
    }
    const int base = blockIdx.x * 2048 + t * 8;
    int c[8], v[8];
    #pragma unroll
    for (int i = 0; i < 8; ++i) {
        c[i] = (base + i < N) ? cnt[base + i] : 0;
        v[i] = (c[i] + 3) & ~3;
    }
    int s = v[0] + v[1] + v[2] + v[3] + v[4] + v[5] + v[6] + v[7];
    const int lane = t & 63, w = t >> 6;
    int incl = s;
    #pragma unroll
    for (int off = 1; off < 64; off <<= 1) {
        int u = __shfl_up(incl, off);
        if (lane >= off) incl += u;
    }
    if (lane == 63) wsum[w] = incl;
    __syncthreads();
    int woff = 0;
    for (int i = 0; i < w; ++i) woff += wsum[i];
    int run = blockoff + woff + (incl - s);
    const int2 zr = {0, 0};
    #pragma unroll
    for (int i = 0; i < 8; ++i) {
        if (base + i < N) {
            row_start[base + i] = run;
            for (int p = c[i]; p < v[i]; ++p) pack[run + p] = zr;   // pad: src=0, norm=0
            run += v[i];
        }
    }
}

// ---------------- fill packed CSR records {src, norm} (8B), no atomics, 8 edges/thread ----------------
__global__ void fill_pack8(const int* __restrict__ src, const int* __restrict__ dst,
                           const int* __restrict__ rank, const int* __restrict__ row_start,
                           const float* __restrict__ dinv, int E, int2* __restrict__ pack) {
    const int q = blockIdx.x * blockDim.x + threadIdx.x;
    const int nq8 = E >> 3;
    if (q < nq8) {
        #pragma unroll
        for (int half = 0; half < 2; ++half) {
            const int4 s = ((const int4*)src)[2 * q + half];
            const int4 d = ((const int4*)dst)[2 * q + half];
            const int4 r = ((const int4*)rank)[2 * q + half];
            int2 p;
            p.x = s.x; p.y = __float_as_int(dinv[s.x] * dinv[d.x]);
            pack[row_start[d.x] + r.x] = p;
            p.x = s.y; p.y = __float_as_int(dinv[s.y] * dinv[d.y]);
            pack[row_start[d.y] + r.y] = p;
            p.x = s.z; p.y = __float_as_int(dinv[s.z] * dinv[d.z]);
            pack[row_start[d.z] + r.z] = p;
            p.x = s.w; p.y = __float_as_int(dinv[s.w] * dinv[d.w]);
            pack[row_start[d.w] + r.w] = p;
        }
    }
    if (q == 0) {   // tail (E not multiple of 8)
        for (int e = nq8 << 3; e < E; ++e) {
            int2 p;
            p.x = src[e]; p.y = __float_as_int(dinv[src[e]] * dinv[dst[e]]);
            pack[row_start[dst[e]] + rank[e]] = p;
        }
    }
}

// ---------------- GEMM2 (MFMA): h2[N,64](bf16) = agg_relu[N,128](bf16) @ W2[128,64] ----------------
// agg already has bias+relu applied -> b-frag is a raw 16B load.
__global__ __launch_bounds__(256) void gemm2_mfma(
        const ushort_t* __restrict__ agg,
        const float* __restrict__ W2, unsigned int* __restrict__ h2,
        int N, int NT, int NW) {
    const int tid  = threadIdx.x;
    const int lane = tid & 63;
    const int m    = lane & 15;
    const int quad = lane >> 4;
    const int gw   = blockIdx.x * 4 + (tid >> 6);

    bf16x8 a[4][4];                         // 4 col-tiles x 4 k-chunks
    #pragma unroll
    for (int ct = 0; ct < 4; ++ct)
        #pragma unroll
        for (int kc = 0; kc < 4; ++kc)
            #pragma unroll
            for (int j = 0; j < 8; ++j)
                a[ct][kc][j] = f2bf_s(W2[(size_t)(kc * 32 + quad * 8 + j) * OUT_DIM + ct * 16 + m]);

    for (int t = gw; t < NT; t += NW) {
        const int n0 = t * 16;
        int node = n0 + m; if (node >= N) node = N - 1;
        const ushort_t* ar = agg + (size_t)node * HID_DIM + quad * 8;
        f32x4 acc[4];
        #pragma unroll
        for (int ct = 0; ct < 4; ++ct) acc[ct] = (f32x4){0.f, 0.f, 0.f, 0.f};
        #pragma unroll
        for (int kc = 0; kc < 4; ++kc) {
            const bf16x8 b = *(const bf16x8*)(ar + kc * 32);
            #pragma unroll
            for (int ct = 0; ct < 4; ++ct)
                acc[ct] = __builtin_amdgcn_mfma_f32_16x16x32_bf16(a[ct][kc], b, acc[ct], 0, 0, 0);
        }
        if (n0 + m < N) {
            unsigned int* o = h2 + (size_t)(n0 + m) * (OUT_DIM / 2) + quad * 2;
            #pragma unroll
            for (int ct = 0; ct < 4; ++ct) {
                uint2 pv;
                pv.x = pack2(acc[ct][0], acc[ct][1]);
                pv.y = pack2(acc[ct][2], acc[ct][3]);
                *(uint2*)(o + ct * 8) = pv;
            }
        }
    }
}

// ---------------- gather aggregation over {src, norm} records, 8 records/iter ----------------
// pad records are {0, 0.0f} -> contribute nothing. bias pre-added (commutes), relu post-loop.
#define GREC(P, HI) do { \
        const ushort4_t v = *(const ushort4_t*)(h + (size_t)(HI ? (P).z : (P).x) * D + f); \
        const float n = __int_as_float(HI ? (P).w : (P).y); \
        acc.x += bf2f(v.x) * n; acc.y += bf2f(v.y) * n; \
        acc.z += bf2f(v.z) * n; acc.w += bf2f(v.w) * n; \
    } while (0)

template<int D, bool BF16_OUT, bool RELU>
__global__ void gather_bf16(const ushort_t* __restrict__ h, const int2* __restrict__ pack,
                            const int* __restrict__ row_start, const int* __restrict__ cnt,
                            const float* __restrict__ dinv, const float* __restrict__ bias,
                            int N, void* __restrict__ outv) {
    const int TPN = D / 4;
    const int NPB = 256 / TPN;
    const int t = threadIdx.x;
    const int node = blockIdx.x * NPB + t / TPN;
    if (node >= N) return;
    const int f = (t & (TPN - 1)) * 4;
    const float dd = dinv[node];

    const ushort4_t self = *(const ushort4_t*)(h + (size_t)node * D + f);
    const float sn = dd * dd;
    float4 acc;
    acc.x = bf2f(self.x) * sn; acc.y = bf2f(self.y) * sn;
    acc.z = bf2f(self.z) * sn; acc.w = bf2f(self.w) * sn;
    const float4 bv = *(const float4*)(bias + f);
    acc.x += bv.x; acc.y += bv.y; acc.z += bv.z; acc.w += bv.w;

    const int2* pk = pack + row_start[node];       // 32B-aligned (start % 4 == 0)
    const int cpad = (cnt[node] + 3) & ~3;
    int e = 0;
    for (; e + 8 <= cpad; e += 8) {                // 8 records in flight (4 int4 + 8 row loads)
        const int4 p0 = *(const int4*)(pk + e);
        const int4 p1 = *(const int4*)(pk + e + 2);
        const int4 p2 = *(const int4*)(pk + e + 4);
        const int4 p3 = *(const int4*)(pk + e + 6);
        GREC(p0, 0); GREC(p0, 1);
        GREC(p1, 0); GREC(p1, 1);
        GREC(p2, 0); GREC(p2, 1);
        GREC(p3, 0); GREC(p3, 1);
    }
    if (e < cpad) {                                // one remaining 4-record quad
        const int4 p0 = *(const int4*)(pk + e);
        const int4 p1 = *(const int4*)(pk + e + 2);
        GREC(p0, 0); GREC(p0, 1);
        GREC(p1, 0); GREC(p1, 1);
    }
    if (RELU) {
        acc.x = fmaxf(acc.x, 0.f); acc.y = fmaxf(acc.y, 0.f);
        acc.z = fmaxf(acc.z, 0.f); acc.w = fmaxf(acc.w, 0.f);
    }
    if (BF16_OUT) {
        unsigned int* out = (unsigned int*)outv;
        uint2 pv;
        pv.x = pack2(acc.x, acc.y);
        pv.y = pack2(acc.z, acc.w);
        *(uint2*)(out + ((size_t)node * D + f) / 2) = pv;
    } else {
        float* out = (float*)outv;
        *(float4*)(out + (size_t)node * D + f) = acc;
    }
}

extern "C" void kernel_launch(void* const* d_in, const int* in_sizes, int n_in,
                              void* d_out, int out_size, void* d_ws, size_t ws_size,
                              hipStream_t stream) {
    const float* x   = (const float*)d_in[0];
    const int*   ei  = (const int*)  d_in[1];
    const float* W1  = (const float*)d_in[2];
    const float* b1  = (const float*)d_in[3];
    const float* W2  = (const float*)d_in[4];
    const float* b2  = (const float*)d_in[5];
    float* out = (float*)d_out;

    const int N = in_sizes[0] / IN_DIM;     // 100000
    const int E = in_sizes[1] / 2;          // 1600000
    const int* src = ei;                    // edge_index[0]
    const int* dst = ei + E;                // edge_index[1]

    // workspace layout (4B units):
    // dinv[N] | cnt[N] | row_start[N] | bsum[1024] | align | pack[E+4N] int2
    // | h1[N*64] u32 (bf16 h1, reused as h2) | agg1[N*64] u32 (bf16; rank aliases it)
    const int PACK_CAP = E + 4 * N;
    float* dinv      = (float*)d_ws;
    int*   cnt       = (int*)(dinv + N);
    int*   row_start = cnt + N;
    int*   bsum      = row_start + N;
    size_t off       = (size_t)(3 * N + 1024);
    off = (off + 3) & ~(size_t)3;           // 16B-align pack
    int2*  pack      = (int2*)((int*)d_ws + off);
    unsigned int* h1 = (unsigned int*)(pack + PACK_CAP);
    unsigned int* agg1 = h1 + (size_t)N * (HID_DIM / 2);
    int*   rank      = (int*)agg1;          // alive only until fill_pack (E <= N*64)
    unsigned int* h2 = h1;                  // reuse after gather128

    const int B = 256;
    const int S = (N + 2047) / 2048;        // scan blocks
    const int NT = (N + 15) / 16;           // 16-node MFMA tiles

    // 1) CSR counts + rank, fused with GEMM1 (independent work hides atomic throughput floor)
    hipMemsetAsync(cnt, 0, (size_t)N * sizeof(int), stream);
    fused_gemm1_count<<<512, 256, 0, stream>>>(x, W1, h1, dst, cnt, rank, N, E, NT);

    // 2) scan (dinv folded into scan_partial; scan_write self-computes block offsets + pads)
    scan_partial<<<S, 256, 0, stream>>>(cnt, bsum, dinv, N);
    scan_write<<<S, 256, 0, stream>>>(cnt, bsum, row_start, pack, N);

    // 3) fill packed CSR records {src, norm}, 8 edges/thread
    fill_pack8<<<((E >> 3) + B - 1) / B, B, 0, stream>>>(src, dst, rank, row_start, dinv, E, pack);

    // 4) agg1 = relu(gather(h1) + b1)  (bf16 out; overwrites rank)
    gather_bf16<HID_DIM, true, true><<<(N + 7) / 8, 256, 0, stream>>>(
        (const ushort_t*)h1, pack, row_start, cnt, dinv, b1, N, (void*)agg1);

    // 5) h2 = agg1 @ W2  (bf16 out, MFMA, raw b-frag loads)
    gemm2_mfma<<<768, 256, 0, stream>>>(
        (const ushort_t*)agg1, W2, h2, N, NT, 768 * 4);

    // 6) out = b2 + gather(h2)  (f32 out)
    gather_bf16<OUT_DIM, false, false><<<(N + 15) / 16, 256, 0, stream>>>(
        (const ushort_t*)h2, pack, row_start, cnt, dinv, b2, N, (void*)out);
}